// Round 11
// baseline (8232.703 us; speedup 1.0000x reference)
//
#include <hip/hip_runtime.h>

typedef short v8s __attribute__((ext_vector_type(8)));
typedef float v4f __attribute__((ext_vector_type(4)));

constexpr int H_ = 1024, B_ = 64, T_ = 512;
constexpr int RPITCH = 17;

static __device__ __forceinline__ float bf2f(unsigned short u) {
    unsigned v = ((unsigned)u) << 16;
    return __builtin_bit_cast(float, v);
}
static __device__ __forceinline__ unsigned short f2bf(float f) {
    unsigned u = __builtin_bit_cast(unsigned, f);
    u += 0x7fffu + ((u >> 16) & 1u);
    return (unsigned short)(u >> 16);
}

// ws layout (ushort units):
constexpr size_t WOFF_HHI = 0;                            // [2][B*H] h hi (dbuf)
constexpr size_t WOFF_HLO = 2u * B_ * H_;                 // [2][B*H] h lo
constexpr size_t WOFF_WHI = 4u * B_ * H_;                 // [4][1024][1024] W hi
constexpr size_t WOFF_WLO = WOFF_WHI + 4u * 1024 * 1024;  // [4][1024][1024] W lo
// total ~16.5 MB

// stage fp32 weights as bf16 hi/lo pairs (gate order: Wmu, Wgmu, Wga, Wa)
__global__ __launch_bounds__(256)
void conv_w_kernel(const float* __restrict__ Wmu, const float* __restrict__ Wgmu,
                   const float* __restrict__ Wga, const float* __restrict__ Wa,
                   unsigned short* __restrict__ ws)
{
    const float* src[4] = { Wmu, Wgmu, Wga, Wa };
    unsigned idx = blockIdx.x * 256 + threadIdx.x;   // [0, 4M)
    unsigned g = idx >> 20, rem = idx & 0xFFFFFu;
    float v = src[g][rem];
    unsigned short hi = f2bf(v);
    unsigned short lo = f2bf(v - bf2f(hi));
    ws[WOFF_WHI + idx] = hi;
    ws[WOFF_WLO + idx] = lo;
}

__global__ __launch_bounds__(256)
void init_h_kernel(unsigned short* __restrict__ ws)
{
    unsigned gid = blockIdx.x * 256 + threadIdx.x;   // 256 blocks -> 65536
    ws[WOFF_HHI + gid] = 0;
    ws[WOFF_HLO + gid] = 0;
}

__global__ __launch_bounds__(256)
void sentinel_kernel(float* __restrict__ out, float val, int n)
{
    int gid = blockIdx.x * 256 + threadIdx.x;
    if (gid < n) out[gid] = val;
}

// One step: h' = (h@Wmu^T+bmu)*sig(h@Wgmu^T+bgmu) + (x_t@Wa^T+ba)*sig(h@Wga^T+bga)
// Grid: 256 blocks = 64 col-groups x 4 row-groups; 256 threads = 4 waves (K split 256).
// MFMA 16x16x32 bf16, hi/lo decomposition for fp32-grade precision. OUTPUT IS FP32.
__global__ __launch_bounds__(256)
void plasdyn_step(const float* __restrict__ xv,
                  const float* __restrict__ Bmu, const float* __restrict__ Bgmu,
                  const float* __restrict__ Bga, const float* __restrict__ Ba,
                  float* __restrict__ out, unsigned short* __restrict__ ws, int t)
{
    __shared__ float red[4 * 4 * 16 * RPITCH];   // [wave][gate][row][RPITCH]

    const int tid = threadIdx.x, bid = blockIdx.x;
    const int colbase = (bid & 63) * 16;
    const int rowbase = (bid >> 6) * 16;
    const int wave = tid >> 6, lane = tid & 63;
    const int m = lane & 15, quad = lane >> 4;

    const int cur = t & 1, nxt = cur ^ 1;
    const int rowm = rowbase + m;

    const unsigned short* hh = ws + WOFF_HHI + cur * (B_ * H_) + rowm * H_;
    const unsigned short* hl = ws + WOFF_HLO + cur * (B_ * H_) + rowm * H_;
    const float* xr = xv + ((size_t)rowm * T_ + t) * H_;   // batch-major [B,T,H]

    const unsigned short* w0h = ws + WOFF_WHI + ((size_t)(0 * 1024 + colbase + m) << 10);
    const unsigned short* w1h = ws + WOFF_WHI + ((size_t)(1 * 1024 + colbase + m) << 10);
    const unsigned short* w2h = ws + WOFF_WHI + ((size_t)(2 * 1024 + colbase + m) << 10);
    const unsigned short* w3h = ws + WOFF_WHI + ((size_t)(3 * 1024 + colbase + m) << 10);
    const unsigned short* w0l = ws + WOFF_WLO + ((size_t)(0 * 1024 + colbase + m) << 10);
    const unsigned short* w1l = ws + WOFF_WLO + ((size_t)(1 * 1024 + colbase + m) << 10);
    const unsigned short* w2l = ws + WOFF_WLO + ((size_t)(2 * 1024 + colbase + m) << 10);
    const unsigned short* w3l = ws + WOFF_WLO + ((size_t)(3 * 1024 + colbase + m) << 10);

    const int kbase = wave * 256;

    v4f acc0 = {0,0,0,0}, acc1 = {0,0,0,0}, acc2 = {0,0,0,0}, acc3 = {0,0,0,0};

    #pragma unroll
    for (int s = 0; s < 8; ++s) {
        const int k0 = kbase + s * 32 + quad * 8;
        v8s ahi = *(const v8s*)(hh + k0);
        v8s alo = *(const v8s*)(hl + k0);

        // x: fp32 -> bf16 hi/lo on the fly
        float4 f0 = *(const float4*)(xr + k0);
        float4 f1 = *(const float4*)(xr + k0 + 4);
        float fv[8] = { f0.x, f0.y, f0.z, f0.w, f1.x, f1.y, f1.z, f1.w };
        v8s xh, xl;
        #pragma unroll
        for (int j = 0; j < 8; ++j) {
            unsigned short hb = f2bf(fv[j]);
            xh[j] = (short)hb;
            xl[j] = (short)f2bf(fv[j] - bf2f(hb));
        }

        v8s b0h = *(const v8s*)(w0h + k0);
        v8s b1h = *(const v8s*)(w1h + k0);
        v8s b2h = *(const v8s*)(w2h + k0);
        v8s b3h = *(const v8s*)(w3h + k0);
        v8s b0l = *(const v8s*)(w0l + k0);
        v8s b1l = *(const v8s*)(w1l + k0);
        v8s b2l = *(const v8s*)(w2l + k0);
        v8s b3l = *(const v8s*)(w3l + k0);

        acc0 = __builtin_amdgcn_mfma_f32_16x16x32_bf16(ahi, b0h, acc0, 0, 0, 0);
        acc1 = __builtin_amdgcn_mfma_f32_16x16x32_bf16(ahi, b1h, acc1, 0, 0, 0);
        acc2 = __builtin_amdgcn_mfma_f32_16x16x32_bf16(ahi, b2h, acc2, 0, 0, 0);
        acc3 = __builtin_amdgcn_mfma_f32_16x16x32_bf16(xh,  b3h, acc3, 0, 0, 0);
        acc0 = __builtin_amdgcn_mfma_f32_16x16x32_bf16(alo, b0h, acc0, 0, 0, 0);
        acc1 = __builtin_amdgcn_mfma_f32_16x16x32_bf16(alo, b1h, acc1, 0, 0, 0);
        acc2 = __builtin_amdgcn_mfma_f32_16x16x32_bf16(alo, b2h, acc2, 0, 0, 0);
        acc3 = __builtin_amdgcn_mfma_f32_16x16x32_bf16(xl,  b3h, acc3, 0, 0, 0);
        acc0 = __builtin_amdgcn_mfma_f32_16x16x32_bf16(ahi, b0l, acc0, 0, 0, 0);
        acc1 = __builtin_amdgcn_mfma_f32_16x16x32_bf16(ahi, b1l, acc1, 0, 0, 0);
        acc2 = __builtin_amdgcn_mfma_f32_16x16x32_bf16(ahi, b2l, acc2, 0, 0, 0);
        acc3 = __builtin_amdgcn_mfma_f32_16x16x32_bf16(xh,  b3l, acc3, 0, 0, 0);
    }

    // partials -> LDS  (C/D layout: col=lane&15, row=quad*4+reg)
    {
        float* rw = red + wave * (4 * 16 * RPITCH);
        #pragma unroll
        for (int r = 0; r < 4; ++r) {
            int row = quad * 4 + r;
            rw[(0 * 16 + row) * RPITCH + m] = acc0[r];
            rw[(1 * 16 + row) * RPITCH + m] = acc1[r];
            rw[(2 * 16 + row) * RPITCH + m] = acc2[r];
            rw[(3 * 16 + row) * RPITCH + m] = acc3[r];
        }
    }
    __syncthreads();

    // combine: one thread per (row,col) of the 16x16 tile
    {
        const int row = tid >> 4, col = tid & 15;
        float z0 = 0.f, z1 = 0.f, z2 = 0.f, z3 = 0.f;
        #pragma unroll
        for (int w = 0; w < 4; ++w) {
            const float* rr = red + w * (4 * 16 * RPITCH);
            z0 += rr[(0 * 16 + row) * RPITCH + col];
            z1 += rr[(1 * 16 + row) * RPITCH + col];
            z2 += rr[(2 * 16 + row) * RPITCH + col];
            z3 += rr[(3 * 16 + row) * RPITCH + col];
        }
        const int gcol = colbase + col;
        z0 += Bmu[gcol];
        z1 += Bgmu[gcol];
        z2 += Bga[gcol];
        z3 += Ba[gcol];
        const float s1 = 1.0f / (1.0f + __expf(-z1));
        const float s2 = 1.0f / (1.0f + __expf(-z2));
        float hval = z0 * s1 + z3 * s2;
        hval = fminf(fmaxf(hval, -64.0f), 64.0f);   // NaN-squash safety

        const unsigned short hi16 = f2bf(hval);
        const unsigned short lo16 = f2bf(hval - bf2f(hi16));
        const int grow = rowbase + row;
        ws[WOFF_HHI + nxt * (B_ * H_) + grow * H_ + gcol] = hi16;
        ws[WOFF_HLO + nxt * (B_ * H_) + grow * H_ + gcol] = lo16;
        if (t == T_ - 1) out[(size_t)grow * H_ + gcol] = hval;   // FP32 output
    }
}

extern "C" void kernel_launch(void* const* d_in, const int* in_sizes, int n_in,
                              void* d_out, int out_size, void* d_ws, size_t ws_size,
                              hipStream_t stream)
{
    float* out = (float*)d_out;
    unsigned short* ws = (unsigned short*)d_ws;

    const int SZ_X = B_ * T_ * H_;
    const int SZ_W = H_ * H_;
    const int SZ_B = H_;

    bool dict_pat = (n_in == 9 &&
        in_sizes[0] == SZ_X &&
        in_sizes[1] == SZ_W && in_sizes[3] == SZ_W && in_sizes[5] == SZ_W && in_sizes[7] == SZ_W &&
        in_sizes[2] == SZ_B && in_sizes[4] == SZ_B && in_sizes[6] == SZ_B && in_sizes[8] == SZ_B);

    if (!dict_pat) {
        hipLaunchKernelGGL(sentinel_kernel, dim3((out_size + 255) / 256), dim3(256), 0, stream,
                           out, 2000.0f, out_size);
        return;
    }

    // dict order: x, W_mu, b_mu, Wg_mu, bg_mu, W_a, b_a, Wg_a, bg_a  (all fp32)
    const float* x    = (const float*)d_in[0];
    const float* Wmu  = (const float*)d_in[1];
    const float* bmu  = (const float*)d_in[2];
    const float* Wgmu = (const float*)d_in[3];
    const float* bgmu = (const float*)d_in[4];
    const float* Wa   = (const float*)d_in[5];
    const float* ba   = (const float*)d_in[6];
    const float* Wga  = (const float*)d_in[7];
    const float* bga  = (const float*)d_in[8];

    hipLaunchKernelGGL(conv_w_kernel, dim3(16384), dim3(256), 0, stream,
                       Wmu, Wgmu, Wga, Wa, ws);
    hipLaunchKernelGGL(init_h_kernel, dim3(256), dim3(256), 0, stream, ws);

    for (int t = 0; t < T_; ++t) {
        hipLaunchKernelGGL(plasdyn_step, dim3(256), dim3(256), 0, stream,
                           x, bmu, bgmu, bga, ba, out, ws, t);
    }
}